// Round 14
// baseline (196.263 us; speedup 1.0000x reference)
//
#include <hip/hip_runtime.h>
#include <math.h>

// Problem constants (from reference)
#define KK     500   // info bits
#define MM     500   // parity checks
#define NNODES 1000  // N = K + M variable nodes
#define NSYM   250   // N / BPS
#define NITERS 5
#define MAXVDEG 4    // info vars degree exactly 3 (row weight of P), parity vars 1
#define EMAX   2048  // E = 2000 edges
#define TB     256
#define LTB    64    // k_lmmse block size (1 wave)

// ---------------- setup: graph build + bit packing + bf output -------------
// Slot layout per check c: info edges in coff[c]..coff[c+1]-2 (atomic order),
// the single parity edge (var >= KK) pinned to coff[c+1]-1 so the BP product
// loop can skip it and use a register-cached constant instead.
__global__ void __launch_bounds__(512)
k_setup(const int* __restrict__ cn, const int* __restrict__ vn, int E,
        const float* __restrict__ ebno, const int* __restrict__ P,
        const int* __restrict__ b, int ncw,
        int* __restrict__ cinfo, int* __restrict__ vlist, int* __restrict__ coff,
        double* __restrict__ nobuf, unsigned* __restrict__ Ppack,
        unsigned* __restrict__ bpack, float* __restrict__ out, int packBlocks) {
  __shared__ int sdeg[512];
  __shared__ int ssc[512];
  __shared__ int scur[512];
  __shared__ int svc[NNODES];
  int tid = threadIdx.x;
  int bx = blockIdx.x;

  if (bx == 0) {
    sdeg[tid] = 0;
    for (int n = tid; n < NNODES; n += 512) svc[n] = 0;
    __syncthreads();
    for (int e = tid; e < E; e += 512) atomicAdd(&sdeg[cn[e]], 1);
    __syncthreads();
    int v = sdeg[tid];
    ssc[tid] = v;
    __syncthreads();
    for (int o = 1; o < 512; o <<= 1) {
      int x = (tid >= o) ? ssc[tid - o] : 0;
      __syncthreads();
      ssc[tid] += x;
      __syncthreads();
    }
    int excl = ssc[tid] - v;
    scur[tid] = excl;
    if (tid < MM) {
      coff[tid] = excl;
      if (tid == MM - 1) coff[MM] = ssc[tid];
    }
    __syncthreads();
    for (int e = tid; e < E; e += 512) {
      int c = cn[e], n = vn[e];
      int slot;
      if (n >= KK) {
        slot = ssc[c] - 1;               // parity edge -> last slot of check c
      } else {
        slot = atomicAdd(&scur[c], 1);   // info edges fill coff[c]..coff[c+1]-2
      }
      cinfo[slot] = (c << 16) | n;
      if (n < KK) {
        int t = atomicAdd(&svc[n], 1);
        if (t < MAXVDEG) vlist[n * MAXVDEG + t] = slot;
      }
    }
    if (tid == 0) {
      double no = 1.0 / (pow(10.0, (double)ebno[0] * 0.1) * 2.0);  // BPS*RATE = 2
      nobuf[0] = no;
      nobuf[1] = sqrt(no * 0.5);
    }
    return;
  }

  if (bx <= packBlocks) {
    int id = (bx - 1) * 512 + tid;
    if (id < MM * 16) {
      int j = id >> 4, w = id & 15;
      unsigned word = 0u;
      int base = w * 32;
      for (int bit = 0; bit < 32; ++bit) {
        int i = base + bit;
        if (i < KK && P[i * MM + j] != 0) word |= (1u << bit);
      }
      Ppack[j * 16 + w] = word;
    } else {
      int id2 = id - MM * 16;
      if (id2 < ncw * 16) {
        int cw = id2 >> 4, w = id2 & 15;
        unsigned word = 0u;
        int base = w * 32;
        for (int bit = 0; bit < 32; ++bit) {
          int i = base + bit;
          if (i < KK && b[cw * KK + i] != 0) word |= (1u << bit);
        }
        bpack[cw * 16 + w] = word;
      }
    }
    return;
  }

  int id = (bx - 1 - packBlocks) * 512 + tid;
  if (id < ncw * KK) out[id] = (float)b[id];
}

// ---------------- 16-QAM constellation (fp64 for TX symbol) ----------------
__device__ __forceinline__ void qam_point(int p, double& re, double& im) {
  const double s = 0.31622776601683794;  // 1/sqrt(10)
  int b0 = (p >> 3) & 1, b1 = (p >> 2) & 1, b2 = (p >> 1) & 1, b3 = p & 1;
  re = (double)((1 - 2 * b0) * (2 - (1 - 2 * b2))) * s;
  im = (double)((1 - 2 * b1) * (2 - (1 - 2 * b3))) * s;
}

// ---------------- channel + LMMSE + max-log LLR --------------------------
// Round-13 analysis: latency-bound with only ~3.8 waves/SIMD of total work
// (VALUBusy 22%, ideal issue time ~7 us vs 46 us measured).  This version
// processes TWO independent symbols per thread (g and g+T/2): two separate
// dependency chains interleave in the pipeline, doubling per-wave issue
// density.  Math per symbol unchanged from round 13 (rsqrt Cholesky, fp32
// demap ratios).
__global__ void __launch_bounds__(LTB, 1)
k_lmmse(const float* __restrict__ h_re, const float* __restrict__ h_im,
        const float* __restrict__ n_re, const float* __restrict__ n_im,
        const double* __restrict__ nobuf,
        const unsigned* __restrict__ bpack, const unsigned* __restrict__ Ppack,
        float* __restrict__ Lch3, int T, int ncw) {
  int gid = blockIdx.x * blockDim.x + threadIdx.x;
  int Th = (T + 1) >> 1;
  if (gid >= Th) return;
  int ts[2];
  ts[0] = gid;
  ts[1] = (gid + Th < T) ? (gid + Th) : gid;  // odd-T guard (duplicate work, same store)

  double no = nobuf[0];
  double sq = nobuf[1];
  const double is2 = 0.7071067811865475244;  // 1/sqrt(2)

  // ---- loads for both symbols up front (independent, overlap) ----
  double Hr[2][4][4], Hi[2][4][4];
  #pragma unroll
  for (int u = 0; u < 2; ++u) {
    int t = ts[u];
    const float4* hr4 = (const float4*)h_re;
    const float4* hi4 = (const float4*)h_im;
    #pragma unroll
    for (int i = 0; i < 4; ++i) {
      float4 a = hr4[t * 4 + i], c = hi4[t * 4 + i];
      Hr[u][i][0] = (double)a.x * is2; Hr[u][i][1] = (double)a.y * is2;
      Hr[u][i][2] = (double)a.z * is2; Hr[u][i][3] = (double)a.w * is2;
      Hi[u][i][0] = (double)c.x * is2; Hi[u][i][1] = (double)c.y * is2;
      Hi[u][i][2] = (double)c.z * is2; Hi[u][i][3] = (double)c.w * is2;
    }
  }
  float4 wr[2], wi[2];
  #pragma unroll
  for (int u = 0; u < 2; ++u) {
    wr[u] = ((const float4*)n_re)[ts[u]];
    wi[u] = ((const float4*)n_im)[ts[u]];
  }

  // ---- transmitted symbols (encode+map inline), both symbols ----
  int btu[2], su[2];
  double xr[2][4], xi[2][4];
  #pragma unroll
  for (int u = 0; u < 2; ++u) {
    int t = ts[u];
    int bt = t / NSYM, s = t - bt * NSYM;
    btu[u] = bt; su[u] = s;
    #pragma unroll
    for (int ue = 0; ue < 4; ++ue) {
      const unsigned* bp = bpack + (bt * 4 + ue) * 16;
      int v = 0;
      #pragma unroll
      for (int k = 0; k < 4; ++k) {
        int n = 4 * s + k;
        int bit;
        if (n < KK) {
          bit = (bp[n >> 5] >> (n & 31)) & 1;
        } else {
          const unsigned* pp = Ppack + (n - KK) * 16;
          int cnt = 0;
          #pragma unroll
          for (int w = 0; w < 16; ++w) cnt += __popc(bp[w] & pp[w]);
          bit = cnt & 1;
        }
        v = (v << 1) | bit;  // MSB-first: weights 8,4,2,1
      }
      qam_point(v, xr[u][ue], xi[u][ue]);
    }
  }

  // ---- heavy math, unrolled over the two independent symbols ----
  #pragma unroll
  for (int u = 0; u < 2; ++u) {
    // y = H x + w
    double yr[4], yi[4];
    {
      float wrv[4] = {wr[u].x, wr[u].y, wr[u].z, wr[u].w};
      float wiv[4] = {wi[u].x, wi[u].y, wi[u].z, wi[u].w};
      #pragma unroll
      for (int i = 0; i < 4; ++i) {
        double ar = (double)wrv[i] * sq;
        double ai = (double)wiv[i] * sq;
        #pragma unroll
        for (int j = 0; j < 4; ++j) {
          ar += Hr[u][i][j] * xr[u][j] - Hi[u][i][j] * xi[u][j];
          ai += Hr[u][i][j] * xi[u][j] + Hi[u][i][j] * xr[u][j];
        }
        yr[i] = ar; yi[i] = ai;
      }
    }

    // A = H H^H + no I, lower triangle, into scalars
    auto dotc = [&](int i, int j, double& ar, double& ai) {
      double r = 0.0, m = 0.0;
      #pragma unroll
      for (int k = 0; k < 4; ++k) {
        r += Hr[u][i][k] * Hr[u][j][k] + Hi[u][i][k] * Hi[u][j][k];
        m += Hi[u][i][k] * Hr[u][j][k] - Hr[u][i][k] * Hi[u][j][k];
      }
      ar = r; ai = m;
    };
    double a00, a11, a22, a33, dum;
    double a10r, a10i, a20r, a20i, a21r, a21i, a30r, a30i, a31r, a31i, a32r, a32i;
    dotc(0, 0, a00, dum);  a00 += no;
    dotc(1, 0, a10r, a10i);
    dotc(1, 1, a11, dum);  a11 += no;
    dotc(2, 0, a20r, a20i);
    dotc(2, 1, a21r, a21i);
    dotc(2, 2, a22, dum);  a22 += no;
    dotc(3, 0, a30r, a30i);
    dotc(3, 1, a31r, a31i);
    dotc(3, 2, a32r, a32i);
    dotc(3, 3, a33, dum);  a33 += no;

    // Cholesky in inverse-diagonal form: i_jj = rsqrt(d_jj)
    double i00 = rsqrt(a00);
    double L10r = a10r * i00, L10i = a10i * i00;
    double L20r = a20r * i00, L20i = a20i * i00;
    double L30r = a30r * i00, L30i = a30i * i00;
    double d11 = a11 - (L10r * L10r + L10i * L10i);
    double i11 = rsqrt(d11);
    double L21r = (a21r - (L20r * L10r + L20i * L10i)) * i11;
    double L21i = (a21i - (L20i * L10r - L20r * L10i)) * i11;
    double L31r = (a31r - (L30r * L10r + L30i * L10i)) * i11;
    double L31i = (a31i - (L30i * L10r - L30r * L10i)) * i11;
    double d22 = a22 - (L20r * L20r + L20i * L20i) - (L21r * L21r + L21i * L21i);
    double i22 = rsqrt(d22);
    double L32r = (a32r - (L30r * L20r + L30i * L20i) - (L31r * L21r + L31i * L21i)) * i22;
    double L32i = (a32i - (L30i * L20r - L30r * L20i) - (L31i * L21r - L31r * L21i)) * i22;
    double d33 = a33 - (L30r * L30r + L30i * L30i) - (L31r * L31r + L31i * L31i)
                     - (L32r * L32r + L32i * L32i);
    double i33 = rsqrt(d33);

    // forward solve: U = L^{-1} H (in place on H[u]), v = L^{-1} y
    #pragma unroll
    for (int j = 0; j < 4; ++j) {
      double u0r = Hr[u][0][j] * i00,               u0i = Hi[u][0][j] * i00;
      double u1r = (Hr[u][1][j] - (L10r * u0r - L10i * u0i)) * i11;
      double u1i = (Hi[u][1][j] - (L10r * u0i + L10i * u0r)) * i11;
      double u2r = (Hr[u][2][j] - (L20r * u0r - L20i * u0i) - (L21r * u1r - L21i * u1i)) * i22;
      double u2i = (Hi[u][2][j] - (L20r * u0i + L20i * u0r) - (L21r * u1i + L21i * u1r)) * i22;
      double u3r = (Hr[u][3][j] - (L30r * u0r - L30i * u0i) - (L31r * u1r - L31i * u1i)
                                - (L32r * u2r - L32i * u2i)) * i33;
      double u3i = (Hi[u][3][j] - (L30r * u0i + L30i * u0r) - (L31r * u1i + L31i * u1r)
                                - (L32r * u2i + L32i * u2r)) * i33;
      Hr[u][0][j] = u0r; Hi[u][0][j] = u0i; Hr[u][1][j] = u1r; Hi[u][1][j] = u1i;
      Hr[u][2][j] = u2r; Hi[u][2][j] = u2i; Hr[u][3][j] = u3r; Hi[u][3][j] = u3i;
    }
    {
      double v0r = yr[0] * i00,               v0i = yi[0] * i00;
      double v1r = (yr[1] - (L10r * v0r - L10i * v0i)) * i11;
      double v1i = (yi[1] - (L10r * v0i + L10i * v0r)) * i11;
      double v2r = (yr[2] - (L20r * v0r - L20i * v0i) - (L21r * v1r - L21i * v1i)) * i22;
      double v2i = (yi[2] - (L20r * v0i + L20i * v0r) - (L21r * v1i + L21i * v1r)) * i22;
      double v3r = (yr[3] - (L30r * v0r - L30i * v0i) - (L31r * v1r - L31i * v1i)
                          - (L32r * v2r - L32i * v2i)) * i33;
      double v3i = (yi[3] - (L30r * v0i + L30i * v0r) - (L31r * v1i + L31i * v1r)
                          - (L32r * v2i + L32i * v2r)) * i33;
      yr[0] = v0r; yi[0] = v0i; yr[1] = v1r; yi[1] = v1i;
      yr[2] = v2r; yi[2] = v2i; yr[3] = v3r; yi[3] = v3i;
    }

    // fp32 16-QAM table
    const float PRT[16] = { 0.31622776601683794f, 0.31622776601683794f, 0.9486832980505138f, 0.9486832980505138f,
                            0.31622776601683794f, 0.31622776601683794f, 0.9486832980505138f, 0.9486832980505138f,
                           -0.31622776601683794f,-0.31622776601683794f,-0.9486832980505138f,-0.9486832980505138f,
                           -0.31622776601683794f,-0.31622776601683794f,-0.9486832980505138f,-0.9486832980505138f };
    const float PIT[16] = { 0.31622776601683794f, 0.9486832980505138f, 0.31622776601683794f, 0.9486832980505138f,
                           -0.31622776601683794f,-0.9486832980505138f,-0.31622776601683794f,-0.9486832980505138f,
                            0.31622776601683794f, 0.9486832980505138f, 0.31622776601683794f, 0.9486832980505138f,
                           -0.31622776601683794f,-0.9486832980505138f,-0.31622776601683794f,-0.9486832980505138f };

    float llr[4][4];  // [bit k][ue j]
    #pragma unroll
    for (int j = 0; j < 4; ++j) {
      double dj = 0.0, rr = 0.0, ri = 0.0;
      #pragma unroll
      for (int i = 0; i < 4; ++i) {
        dj += Hr[u][i][j] * Hr[u][i][j] + Hi[u][i][j] * Hi[u][i][j];
        rr += Hr[u][i][j] * yr[i] + Hi[u][i][j] * yi[i];
        ri += Hr[u][i][j] * yi[i] - Hi[u][i][j] * yr[i];
      }
      // fp32 ratios (reference is fp32 here); 1-dj subtracted in fp64 first.
      float djf = (float)dj;
      float rdj = __fdividef(1.0f, djf);
      float xhr = (float)rr * rdj, xhi = (float)ri * rdj;
      float gap = (float)(1.0 - dj);
      float inoe = __fdividef(djf, fmaxf(gap, djf * 1e-12f));

      float m0[4] = {-1e30f, -1e30f, -1e30f, -1e30f};
      float m1[4] = {-1e30f, -1e30f, -1e30f, -1e30f};
      #pragma unroll
      for (int p = 0; p < 16; ++p) {
        float dr = xhr - PRT[p], di = xhi - PIT[p];
        float met = -(dr * dr + di * di) * inoe;
        #pragma unroll
        for (int k = 0; k < 4; ++k) {
          if ((p >> (3 - k)) & 1) m1[k] = fmaxf(m1[k], met);
          else                    m0[k] = fmaxf(m0[k], met);
        }
      }
      #pragma unroll
      for (int k = 0; k < 4; ++k) llr[k][j] = m0[k] - m1[k];
    }

    // store: plane 0 = ue{0,1}, plane 1 = ue{2,3}
    float2* pl0 = (float2*)(Lch3 + (size_t)btu[u] * (NNODES * 4));
    float2* pl1 = pl0 + NNODES;
    #pragma unroll
    for (int k = 0; k < 4; ++k) {
      int node = 4 * su[u] + k;
      pl0[node] = make_float2(llr[k][0], llr[k][1]);
      pl1[node] = make_float2(llr[k][2], llr[k][3]);
    }
  }
}

// ---------------- fused LDS-resident BP decoder, 2 codewords / block --------
// Division-free pass-1: (A-B)/(A+B) invariant under common scale; factor
// pairs scaled by their own t (a' = t + Pc, b' = t - Pc).  Parity edges
// (one per check, constant t) factored into a register (qpar); product loop
// runs [beg, end-1).
__device__ __forceinline__ float tanh_half(float m) {
  float mc = fminf(fmaxf(m, -19.8f), 19.8f);
  float e = __expf(mc);
  float t = 1.0f - __fdividef(2.0f, e + 1.0f);
  return (t >= 0.0f) ? fmaxf(t, 1e-7f) : fminf(t, -1e-7f);
}
__device__ __forceinline__ float pclip(float P, float t) {
  // t * clip(P/t, +-0.999999), computed without dividing
  return copysignf(fminf(fabsf(P), 0.999999f * fabsf(t)), P);
}
__device__ __forceinline__ float tfloor(float t) {
  return (t >= 0.0f) ? fmaxf(t, 1e-7f) : fminf(t, -1e-7f);
}
__device__ __forceinline__ float atanh2c(float P, float t) {
  float r = __fdividef(P, t);
  r = fminf(fmaxf(r, -0.999999f), 0.999999f);
  return __logf(__fdividef(1.0f + r, 1.0f - r));
}

__global__ void __launch_bounds__(256) k_bp(const float* __restrict__ Lch3,
                                            const int* __restrict__ vlist,
                                            const int* __restrict__ coff,
                                            const int* __restrict__ cinfo,
                                            float* __restrict__ out, int E, int ncw) {
  __shared__ float2 sT[EMAX];   // tanh(v2c/2) per info-edge slot (16 KB)
  __shared__ float2 sP[512];    // per-check product of tanh (4 KB)

  int tid = threadIdx.x;
  int pairId = blockIdx.x;  // = bt*2 + plane; codewords 2*pairId, 2*pairId+1

  const float2* src = (const float2*)(Lch3 + (size_t)pairId * (NNODES * 2));

  // own info-node state in registers
  float2 Ln[2], En[2];
  int pk0[2], pk1[2], pk2[2]; bool iok[2];
  #pragma unroll
  for (int i = 0; i < 2; ++i) {
    int n = tid + TB * i;
    iok[i] = n < KK;
    Ln[i] = make_float2(0.f, 0.f);
    En[i] = make_float2(1.f, 1.f);
    pk0[i] = pk1[i] = pk2[i] = 0;
    if (iok[i]) {
      float2 L = src[n];
      Ln[i] = L;
      En[i] = make_float2(__expf(fminf(fmaxf(L.x, -55.f), 55.f)),
                          __expf(fminf(fmaxf(L.y, -55.f), 55.f)));
      int s0 = vlist[n * MAXVDEG], s1 = vlist[n * MAXVDEG + 1], s2 = vlist[n * MAXVDEG + 2];
      pk0[i] = (cinfo[s0] & 0xffff0000) | s0;
      pk1[i] = (cinfo[s1] & 0xffff0000) | s1;
      pk2[i] = (cinfo[s2] & 0xffff0000) | s2;
    }
  }
  // per-check constant: tanh of the parity-node LLR (check c <-> parity var KK+c)
  float2 qpar0, qpar1;
  {
    float2 Lp0 = src[KK + tid];
    qpar0 = make_float2(tanh_half(Lp0.x), tanh_half(Lp0.y));
  }
  bool c1ok = (tid + TB) < MM;
  if (c1ok) {
    float2 Lp1 = src[KK + tid + TB];
    qpar1 = make_float2(tanh_half(Lp1.x), tanh_half(Lp1.y));
  } else {
    qpar1 = make_float2(1.f, 1.f);
  }
  int beg0 = coff[tid], end0 = coff[tid + 1];
  int beg1 = c1ok ? coff[tid + TB] : 0;
  int end1 = c1ok ? coff[tid + TB + 1] : 0;
  // no barrier needed: first sT reads happen in pass 2, after the in-loop barrier

  for (int it = 0; it < NITERS; ++it) {
    // ---- pass 1: info-node var update ----
    if (it == 0) {
      #pragma unroll
      for (int i = 0; i < 2; ++i) {
        if (iok[i]) {
          float2 t = make_float2(tanh_half(Ln[i].x), tanh_half(Ln[i].y));
          sT[pk0[i] & 0xffff] = t;
          sT[pk1[i] & 0xffff] = t;
          sT[pk2[i] & 0xffff] = t;
        }
      }
    } else {
      #pragma unroll
      for (int i = 0; i < 2; ++i) {
        if (iok[i]) {
          int s0 = pk0[i] & 0xffff, c0 = ((unsigned)pk0[i]) >> 16;
          int s1 = pk1[i] & 0xffff, c1 = ((unsigned)pk1[i]) >> 16;
          int s2 = pk2[i] & 0xffff, c2 = ((unsigned)pk2[i]) >> 16;
          float2 P0 = sP[c0], P1 = sP[c1], P2 = sP[c2];
          float2 t0 = sT[s0], t1 = sT[s1], t2 = sT[s2];
          // lane x
          float p0 = pclip(P0.x, t0.x), p1 = pclip(P1.x, t1.x), p2 = pclip(P2.x, t2.x);
          float a0 = t0.x + p0, a1 = t1.x + p1, a2 = t2.x + p2;
          float b0 = t0.x - p0, b1 = t1.x - p1, b2 = t2.x - p2;
          float Ex = En[i].x;
          float A0 = Ex * (a1 * a2), A1 = Ex * (a0 * a2), A2 = Ex * (a0 * a1);
          float B0 = b1 * b2,        B1 = b0 * b2,        B2 = b0 * b1;
          float n0x = tfloor(__fdividef(A0 - B0, A0 + B0));
          float n1x = tfloor(__fdividef(A1 - B1, A1 + B1));
          float n2x = tfloor(__fdividef(A2 - B2, A2 + B2));
          // lane y
          float q0 = pclip(P0.y, t0.y), q1 = pclip(P1.y, t1.y), q2 = pclip(P2.y, t2.y);
          float c0a = t0.y + q0, c1a = t1.y + q1, c2a = t2.y + q2;
          float d0b = t0.y - q0, d1b = t1.y - q1, d2b = t2.y - q2;
          float Ey = En[i].y;
          float C0 = Ey * (c1a * c2a), C1 = Ey * (c0a * c2a), C2 = Ey * (c0a * c1a);
          float D0 = d1b * d2b,        D1 = d0b * d2b,        D2 = d0b * d1b;
          float n0y = tfloor(__fdividef(C0 - D0, C0 + D0));
          float n1y = tfloor(__fdividef(C1 - D1, C1 + D1));
          float n2y = tfloor(__fdividef(C2 - D2, C2 + D2));
          sT[s0] = make_float2(n0x, n0y);
          sT[s1] = make_float2(n1x, n1y);
          sT[s2] = make_float2(n2x, n2y);
        }
      }
    }
    __syncthreads();
    // ---- pass 2: per-check products (parity factor from register) ----
    {
      float px = qpar0.x, py = qpar0.y;
      for (int e = beg0; e < end0 - 1; ++e) { float2 tt = sT[e]; px *= tt.x; py *= tt.y; }
      sP[tid] = make_float2(px, py);
      if (c1ok) {
        float qx = qpar1.x, qy = qpar1.y;
        for (int e = beg1; e < end1 - 1; ++e) { float2 tt = sT[e]; qx *= tt.x; qy *= tt.y; }
        sP[tid + TB] = make_float2(qx, qy);
      }
    }
    __syncthreads();
  }

  // ---- decide: additive log form (once) ----
  int cw0 = pairId * 2;
  float* o0 = out + (size_t)ncw * KK + (size_t)cw0 * KK;
  float* o1 = o0 + KK;
  #pragma unroll
  for (int i = 0; i < 2; ++i) {
    if (iok[i]) {
      int n = tid + TB * i;
      int s0 = pk0[i] & 0xffff, c0 = ((unsigned)pk0[i]) >> 16;
      int s1 = pk1[i] & 0xffff, c1 = ((unsigned)pk1[i]) >> 16;
      int s2 = pk2[i] & 0xffff, c2 = ((unsigned)pk2[i]) >> 16;
      float2 P0 = sP[c0], P1 = sP[c1], P2 = sP[c2];
      float2 t0 = sT[s0], t1 = sT[s1], t2 = sT[s2];
      float2 L = Ln[i];
      float ax = L.x + atanh2c(P0.x, t0.x) + atanh2c(P1.x, t1.x) + atanh2c(P2.x, t2.x);
      float ay = L.y + atanh2c(P0.y, t0.y) + atanh2c(P1.y, t1.y) + atanh2c(P2.y, t2.y);
      o0[n] = (ax < 0.0f) ? 1.0f : 0.0f;
      o1[n] = (ay < 0.0f) ? 1.0f : 0.0f;
    }
  }
}

// ---------------- launcher ----------------
extern "C" void kernel_launch(void* const* d_in, const int* in_sizes, int n_in,
                              void* d_out, int out_size, void* d_ws, size_t ws_size,
                              hipStream_t stream) {
  const float* ebno = (const float*)d_in[1];
  const int*   b    = (const int*)d_in[2];
  const int*   P    = (const int*)d_in[3];
  const int*   cn   = (const int*)d_in[4];
  const int*   vn   = (const int*)d_in[5];
  const float* h_re = (const float*)d_in[6];
  const float* h_im = (const float*)d_in[7];
  const float* nre  = (const float*)d_in[8];
  const float* nim  = (const float*)d_in[9];
  float* out = (float*)d_out;

  int E     = in_sizes[4];
  int batch = in_sizes[2] / (4 * KK);
  int ncw   = batch * 4;
  int T     = batch * NSYM;

  char* ws = (char*)d_ws;
  size_t off = 0;
  auto alloc = [&](size_t bytes) -> void* {
    void* p = ws + off;
    off += (bytes + 255) & ~(size_t)255;
    return p;
  };
  float*    Lch3   = (float*)alloc((size_t)NNODES * ncw * 4);
  unsigned* Ppack  = (unsigned*)alloc((size_t)MM * 16 * 4);
  unsigned* bpack  = (unsigned*)alloc((size_t)ncw * 16 * 4);
  int*      coff   = (int*)alloc((size_t)(MM + 1) * 4);
  int*      cinfo  = (int*)alloc((size_t)EMAX * 4);
  int*      vlist  = (int*)alloc((size_t)NNODES * MAXVDEG * 4);
  double*   nobuf  = (double*)alloc(2 * 8);
  (void)ws_size; (void)n_in; (void)out_size;

  int packItems  = MM * 16 + ncw * 16;
  int packBlocks = (packItems + 511) / 512;
  int bfBlocks   = (ncw * KK + 511) / 512;
  int setupGrid  = 1 + packBlocks + bfBlocks;

  k_setup<<<dim3(setupGrid), dim3(512), 0, stream>>>(cn, vn, E, ebno, P, b, ncw,
                                                     cinfo, vlist, coff, nobuf,
                                                     Ppack, bpack, out, packBlocks);
  int Th = (T + 1) >> 1;
  k_lmmse<<<dim3((Th + LTB - 1) / LTB), dim3(LTB), 0, stream>>>(h_re, h_im, nre, nim, nobuf,
                                                                bpack, Ppack, Lch3, T, ncw);
  k_bp<<<dim3(ncw / 2), dim3(TB), 0, stream>>>(Lch3, vlist, coff, cinfo, out, E, ncw);
}

// Round 15
// 193.338 us; speedup vs baseline: 1.0151x; 1.0151x over previous
//
#include <hip/hip_runtime.h>
#include <math.h>

// Problem constants (from reference)
#define KK     500   // info bits
#define MM     500   // parity checks
#define NNODES 1000  // N = K + M variable nodes
#define NSYM   250   // N / BPS
#define NITERS 5
#define MAXVDEG 4    // info vars degree exactly 3 (row weight of P), parity vars 1
#define EMAX   2048  // E = 2000 edges
#define TB     256
#define LTB    64    // k_lmmse block size (1 wave)

// ---------------- setup: graph build + bit packing + bf output -------------
// Slot layout per check c: info edges in coff[c]..coff[c+1]-2 (atomic order),
// the single parity edge (var >= KK) pinned to coff[c+1]-1 so the BP product
// loop can skip it and use a register-cached constant instead.
__global__ void __launch_bounds__(512)
k_setup(const int* __restrict__ cn, const int* __restrict__ vn, int E,
        const float* __restrict__ ebno, const int* __restrict__ P,
        const int* __restrict__ b, int ncw,
        int* __restrict__ cinfo, int* __restrict__ vlist, int* __restrict__ coff,
        double* __restrict__ nobuf, unsigned* __restrict__ Ppack,
        unsigned* __restrict__ bpack, float* __restrict__ out, int packBlocks) {
  __shared__ int sdeg[512];
  __shared__ int ssc[512];
  __shared__ int scur[512];
  __shared__ int svc[NNODES];
  int tid = threadIdx.x;
  int bx = blockIdx.x;

  if (bx == 0) {
    sdeg[tid] = 0;
    for (int n = tid; n < NNODES; n += 512) svc[n] = 0;
    __syncthreads();
    for (int e = tid; e < E; e += 512) atomicAdd(&sdeg[cn[e]], 1);
    __syncthreads();
    int v = sdeg[tid];
    ssc[tid] = v;
    __syncthreads();
    for (int o = 1; o < 512; o <<= 1) {
      int x = (tid >= o) ? ssc[tid - o] : 0;
      __syncthreads();
      ssc[tid] += x;
      __syncthreads();
    }
    int excl = ssc[tid] - v;
    scur[tid] = excl;
    if (tid < MM) {
      coff[tid] = excl;
      if (tid == MM - 1) coff[MM] = ssc[tid];
    }
    __syncthreads();
    for (int e = tid; e < E; e += 512) {
      int c = cn[e], n = vn[e];
      int slot;
      if (n >= KK) {
        slot = ssc[c] - 1;               // parity edge -> last slot of check c
      } else {
        slot = atomicAdd(&scur[c], 1);   // info edges fill coff[c]..coff[c+1]-2
      }
      cinfo[slot] = (c << 16) | n;
      if (n < KK) {
        int t = atomicAdd(&svc[n], 1);
        if (t < MAXVDEG) vlist[n * MAXVDEG + t] = slot;
      }
    }
    if (tid == 0) {
      double no = 1.0 / (pow(10.0, (double)ebno[0] * 0.1) * 2.0);  // BPS*RATE = 2
      nobuf[0] = no;
      nobuf[1] = sqrt(no * 0.5);
    }
    return;
  }

  if (bx <= packBlocks) {
    int id = (bx - 1) * 512 + tid;
    if (id < MM * 16) {
      int j = id >> 4, w = id & 15;
      unsigned word = 0u;
      int base = w * 32;
      for (int bit = 0; bit < 32; ++bit) {
        int i = base + bit;
        if (i < KK && P[i * MM + j] != 0) word |= (1u << bit);
      }
      Ppack[j * 16 + w] = word;
    } else {
      int id2 = id - MM * 16;
      if (id2 < ncw * 16) {
        int cw = id2 >> 4, w = id2 & 15;
        unsigned word = 0u;
        int base = w * 32;
        for (int bit = 0; bit < 32; ++bit) {
          int i = base + bit;
          if (i < KK && b[cw * KK + i] != 0) word |= (1u << bit);
        }
        bpack[cw * 16 + w] = word;
      }
    }
    return;
  }

  int id = (bx - 1 - packBlocks) * 512 + tid;
  if (id < ncw * KK) out[id] = (float)b[id];
}

// ---------------- 16-QAM constellation (fp64 for TX symbol) ----------------
__device__ __forceinline__ void qam_point(int p, double& re, double& im) {
  const double s = 0.31622776601683794;  // 1/sqrt(10)
  int b0 = (p >> 3) & 1, b1 = (p >> 2) & 1, b2 = (p >> 1) & 1, b3 = p & 1;
  re = (double)((1 - 2 * b0) * (2 - (1 - 2 * b2))) * s;
  im = (double)((1 - 2 * b1) * (2 - (1 - 2 * b3))) * s;
}

// ---------------- channel + LMMSE + max-log LLR --------------------------
// Round-14 post-mortem: intra-thread ILP (2 sym/thread) did NOT interleave
// (in-order issue; VALU busy-cycles unchanged, occupancy halved -> slower).
// TLP is the lever.  This version runs TWO THREADS PER SYMBOL (t, plane):
// channel/A/Cholesky duplicated (~70% of chain), but each thread solves only
// its 2 U-columns, demaps 2 UEs, and stores its own plane.  Wave count
// doubles (3906 -> 7812, ~7.6/SIMD) for ~1.7x total issue -> net win for a
// latency-bound kernel.  Math per value identical to round 13.
__global__ void __launch_bounds__(LTB, 1)
k_lmmse(const float* __restrict__ h_re, const float* __restrict__ h_im,
        const float* __restrict__ n_re, const float* __restrict__ n_im,
        const double* __restrict__ nobuf,
        const unsigned* __restrict__ bpack, const unsigned* __restrict__ Ppack,
        float* __restrict__ Lch3, int T, int ncw) {
  int gid = blockIdx.x * blockDim.x + threadIdx.x;
  if (gid >= 2 * T) return;
  int t = gid >> 1;
  int plane = gid & 1;   // plane 0 = ue{0,1}, plane 1 = ue{2,3}
  int bt = t / NSYM, s = t - bt * NSYM;

  double no = nobuf[0];
  double sq = nobuf[1];
  const double is2 = 0.7071067811865475244;  // 1/sqrt(2)

  double Hr[4][4], Hi[4][4];
  {
    const float4* hr4 = (const float4*)h_re;
    const float4* hi4 = (const float4*)h_im;
    #pragma unroll
    for (int i = 0; i < 4; ++i) {
      float4 a = hr4[t * 4 + i], c = hi4[t * 4 + i];
      Hr[i][0] = (double)a.x * is2; Hr[i][1] = (double)a.y * is2;
      Hr[i][2] = (double)a.z * is2; Hr[i][3] = (double)a.w * is2;
      Hi[i][0] = (double)c.x * is2; Hi[i][1] = (double)c.y * is2;
      Hi[i][2] = (double)c.z * is2; Hi[i][3] = (double)c.w * is2;
    }
  }

  // transmitted symbols: encode+map inline (all 4 UEs needed for y)
  double xr[4], xi[4];
  #pragma unroll
  for (int ue = 0; ue < 4; ++ue) {
    const unsigned* bp = bpack + (bt * 4 + ue) * 16;
    int v = 0;
    #pragma unroll
    for (int k = 0; k < 4; ++k) {
      int n = 4 * s + k;
      int bit;
      if (n < KK) {
        bit = (bp[n >> 5] >> (n & 31)) & 1;
      } else {
        const unsigned* pp = Ppack + (n - KK) * 16;
        int cnt = 0;
        #pragma unroll
        for (int w = 0; w < 16; ++w) cnt += __popc(bp[w] & pp[w]);
        bit = cnt & 1;
      }
      v = (v << 1) | bit;  // MSB-first: weights 8,4,2,1
    }
    qam_point(v, xr[ue], xi[ue]);
  }

  // y = H x + w
  double yr[4], yi[4];
  {
    float4 wr = ((const float4*)n_re)[t];
    float4 wi = ((const float4*)n_im)[t];
    float wrv[4] = {wr.x, wr.y, wr.z, wr.w};
    float wiv[4] = {wi.x, wi.y, wi.z, wi.w};
    #pragma unroll
    for (int i = 0; i < 4; ++i) {
      double ar = (double)wrv[i] * sq;
      double ai = (double)wiv[i] * sq;
      #pragma unroll
      for (int j = 0; j < 4; ++j) {
        ar += Hr[i][j] * xr[j] - Hi[i][j] * xi[j];
        ai += Hr[i][j] * xi[j] + Hi[i][j] * xr[j];
      }
      yr[i] = ar; yi[i] = ai;
    }
  }

  // A = H H^H + no I, lower triangle, into scalars
  auto dotc = [&](int i, int j, double& ar, double& ai) {
    double r = 0.0, m = 0.0;
    #pragma unroll
    for (int k = 0; k < 4; ++k) {
      r += Hr[i][k] * Hr[j][k] + Hi[i][k] * Hi[j][k];
      m += Hi[i][k] * Hr[j][k] - Hr[i][k] * Hi[j][k];
    }
    ar = r; ai = m;
  };
  double a00, a11, a22, a33, dum;
  double a10r, a10i, a20r, a20i, a21r, a21i, a30r, a30i, a31r, a31i, a32r, a32i;
  dotc(0, 0, a00, dum);  a00 += no;
  dotc(1, 0, a10r, a10i);
  dotc(1, 1, a11, dum);  a11 += no;
  dotc(2, 0, a20r, a20i);
  dotc(2, 1, a21r, a21i);
  dotc(2, 2, a22, dum);  a22 += no;
  dotc(3, 0, a30r, a30i);
  dotc(3, 1, a31r, a31i);
  dotc(3, 2, a32r, a32i);
  dotc(3, 3, a33, dum);  a33 += no;

  // Cholesky in inverse-diagonal form: i_jj = rsqrt(d_jj)
  double i00 = rsqrt(a00);
  double L10r = a10r * i00, L10i = a10i * i00;
  double L20r = a20r * i00, L20i = a20i * i00;
  double L30r = a30r * i00, L30i = a30i * i00;
  double d11 = a11 - (L10r * L10r + L10i * L10i);
  double i11 = rsqrt(d11);
  double L21r = (a21r - (L20r * L10r + L20i * L10i)) * i11;
  double L21i = (a21i - (L20i * L10r - L20r * L10i)) * i11;
  double L31r = (a31r - (L30r * L10r + L30i * L10i)) * i11;
  double L31i = (a31i - (L30i * L10r - L30r * L10i)) * i11;
  double d22 = a22 - (L20r * L20r + L20i * L20i) - (L21r * L21r + L21i * L21i);
  double i22 = rsqrt(d22);
  double L32r = (a32r - (L30r * L20r + L30i * L20i) - (L31r * L21r + L31i * L21i)) * i22;
  double L32i = (a32i - (L30i * L20r - L30r * L20i) - (L31i * L21r - L31r * L21i)) * i22;
  double d33 = a33 - (L30r * L30r + L30i * L30i) - (L31r * L31r + L31i * L31i)
                   - (L32r * L32r + L32i * L32i);
  double i33 = rsqrt(d33);

  // v = L^{-1} y
  double v0r = yr[0] * i00,               v0i = yi[0] * i00;
  double v1r = (yr[1] - (L10r * v0r - L10i * v0i)) * i11;
  double v1i = (yi[1] - (L10r * v0i + L10i * v0r)) * i11;
  double v2r = (yr[2] - (L20r * v0r - L20i * v0i) - (L21r * v1r - L21i * v1i)) * i22;
  double v2i = (yi[2] - (L20r * v0i + L20i * v0r) - (L21r * v1i + L21i * v1r)) * i22;
  double v3r = (yr[3] - (L30r * v0r - L30i * v0i) - (L31r * v1r - L31i * v1i)
                      - (L32r * v2r - L32i * v2i)) * i33;
  double v3i = (yi[3] - (L30r * v0i + L30i * v0r) - (L31r * v1i + L31i * v1r)
                      - (L32r * v2i + L32i * v2r)) * i33;

  // fp32 16-QAM table
  const float PRT[16] = { 0.31622776601683794f, 0.31622776601683794f, 0.9486832980505138f, 0.9486832980505138f,
                          0.31622776601683794f, 0.31622776601683794f, 0.9486832980505138f, 0.9486832980505138f,
                         -0.31622776601683794f,-0.31622776601683794f,-0.9486832980505138f,-0.9486832980505138f,
                         -0.31622776601683794f,-0.31622776601683794f,-0.9486832980505138f,-0.9486832980505138f };
  const float PIT[16] = { 0.31622776601683794f, 0.9486832980505138f, 0.31622776601683794f, 0.9486832980505138f,
                         -0.31622776601683794f,-0.9486832980505138f,-0.31622776601683794f,-0.9486832980505138f,
                          0.31622776601683794f, 0.9486832980505138f, 0.31622776601683794f, 0.9486832980505138f,
                         -0.31622776601683794f,-0.9486832980505138f,-0.31622776601683794f,-0.9486832980505138f };

  // solve U columns + demap for THIS PLANE's two UEs only
  float llr[4][2];  // [bit k][local ue jj]
  #pragma unroll
  for (int jj = 0; jj < 2; ++jj) {
    int j = 2 * plane + jj;
    double u0r = Hr[0][j] * i00,               u0i = Hi[0][j] * i00;
    double u1r = (Hr[1][j] - (L10r * u0r - L10i * u0i)) * i11;
    double u1i = (Hi[1][j] - (L10r * u0i + L10i * u0r)) * i11;
    double u2r = (Hr[2][j] - (L20r * u0r - L20i * u0i) - (L21r * u1r - L21i * u1i)) * i22;
    double u2i = (Hi[2][j] - (L20r * u0i + L20i * u0r) - (L21r * u1i + L21i * u1r)) * i22;
    double u3r = (Hr[3][j] - (L30r * u0r - L30i * u0i) - (L31r * u1r - L31i * u1i)
                           - (L32r * u2r - L32i * u2i)) * i33;
    double u3i = (Hi[3][j] - (L30r * u0i + L30i * u0r) - (L31r * u1i + L31i * u1r)
                           - (L32r * u2i + L32i * u2r)) * i33;

    double dj = u0r * u0r + u0i * u0i + u1r * u1r + u1i * u1i
              + u2r * u2r + u2i * u2i + u3r * u3r + u3i * u3i;
    double rr = u0r * v0r + u0i * v0i + u1r * v1r + u1i * v1i
              + u2r * v2r + u2i * v2i + u3r * v3r + u3i * v3i;
    double ri = u0r * v0i - u0i * v0r + u1r * v1i - u1i * v1r
              + u2r * v2i - u2i * v2r + u3r * v3i - u3i * v3r;

    // fp32 ratios (reference is fp32 here); 1-dj subtracted in fp64 first.
    float djf = (float)dj;
    float rdj = __fdividef(1.0f, djf);
    float xhr = (float)rr * rdj, xhi = (float)ri * rdj;
    float gap = (float)(1.0 - dj);
    float inoe = __fdividef(djf, fmaxf(gap, djf * 1e-12f));

    float m0[4] = {-1e30f, -1e30f, -1e30f, -1e30f};
    float m1[4] = {-1e30f, -1e30f, -1e30f, -1e30f};
    #pragma unroll
    for (int p = 0; p < 16; ++p) {
      float dr = xhr - PRT[p], di = xhi - PIT[p];
      float met = -(dr * dr + di * di) * inoe;
      #pragma unroll
      for (int k = 0; k < 4; ++k) {
        if ((p >> (3 - k)) & 1) m1[k] = fmaxf(m1[k], met);
        else                    m0[k] = fmaxf(m0[k], met);
      }
    }
    #pragma unroll
    for (int k = 0; k < 4; ++k) llr[k][jj] = m0[k] - m1[k];
  }

  // store this plane's float2 per node
  float2* pl = (float2*)(Lch3 + (size_t)bt * (NNODES * 4)) + plane * NNODES;
  #pragma unroll
  for (int k = 0; k < 4; ++k) {
    int node = 4 * s + k;
    pl[node] = make_float2(llr[k][0], llr[k][1]);
  }
}

// ---------------- fused LDS-resident BP decoder, 2 codewords / block --------
// Division-free pass-1: (A-B)/(A+B) invariant under common scale; factor
// pairs scaled by their own t (a' = t + Pc, b' = t - Pc).  Parity edges
// (one per check, constant t) factored into a register (qpar); product loop
// runs [beg, end-1).
__device__ __forceinline__ float tanh_half(float m) {
  float mc = fminf(fmaxf(m, -19.8f), 19.8f);
  float e = __expf(mc);
  float t = 1.0f - __fdividef(2.0f, e + 1.0f);
  return (t >= 0.0f) ? fmaxf(t, 1e-7f) : fminf(t, -1e-7f);
}
__device__ __forceinline__ float pclip(float P, float t) {
  // t * clip(P/t, +-0.999999), computed without dividing
  return copysignf(fminf(fabsf(P), 0.999999f * fabsf(t)), P);
}
__device__ __forceinline__ float tfloor(float t) {
  return (t >= 0.0f) ? fmaxf(t, 1e-7f) : fminf(t, -1e-7f);
}
__device__ __forceinline__ float atanh2c(float P, float t) {
  float r = __fdividef(P, t);
  r = fminf(fmaxf(r, -0.999999f), 0.999999f);
  return __logf(__fdividef(1.0f + r, 1.0f - r));
}

__global__ void __launch_bounds__(256) k_bp(const float* __restrict__ Lch3,
                                            const int* __restrict__ vlist,
                                            const int* __restrict__ coff,
                                            const int* __restrict__ cinfo,
                                            float* __restrict__ out, int E, int ncw) {
  __shared__ float2 sT[EMAX];   // tanh(v2c/2) per info-edge slot (16 KB)
  __shared__ float2 sP[512];    // per-check product of tanh (4 KB)

  int tid = threadIdx.x;
  int pairId = blockIdx.x;  // = bt*2 + plane; codewords 2*pairId, 2*pairId+1

  const float2* src = (const float2*)(Lch3 + (size_t)pairId * (NNODES * 2));

  // own info-node state in registers
  float2 Ln[2], En[2];
  int pk0[2], pk1[2], pk2[2]; bool iok[2];
  #pragma unroll
  for (int i = 0; i < 2; ++i) {
    int n = tid + TB * i;
    iok[i] = n < KK;
    Ln[i] = make_float2(0.f, 0.f);
    En[i] = make_float2(1.f, 1.f);
    pk0[i] = pk1[i] = pk2[i] = 0;
    if (iok[i]) {
      float2 L = src[n];
      Ln[i] = L;
      En[i] = make_float2(__expf(fminf(fmaxf(L.x, -55.f), 55.f)),
                          __expf(fminf(fmaxf(L.y, -55.f), 55.f)));
      int s0 = vlist[n * MAXVDEG], s1 = vlist[n * MAXVDEG + 1], s2 = vlist[n * MAXVDEG + 2];
      pk0[i] = (cinfo[s0] & 0xffff0000) | s0;
      pk1[i] = (cinfo[s1] & 0xffff0000) | s1;
      pk2[i] = (cinfo[s2] & 0xffff0000) | s2;
    }
  }
  // per-check constant: tanh of the parity-node LLR (check c <-> parity var KK+c)
  float2 qpar0, qpar1;
  {
    float2 Lp0 = src[KK + tid];
    qpar0 = make_float2(tanh_half(Lp0.x), tanh_half(Lp0.y));
  }
  bool c1ok = (tid + TB) < MM;
  if (c1ok) {
    float2 Lp1 = src[KK + tid + TB];
    qpar1 = make_float2(tanh_half(Lp1.x), tanh_half(Lp1.y));
  } else {
    qpar1 = make_float2(1.f, 1.f);
  }
  int beg0 = coff[tid], end0 = coff[tid + 1];
  int beg1 = c1ok ? coff[tid + TB] : 0;
  int end1 = c1ok ? coff[tid + TB + 1] : 0;
  // no barrier needed: first sT reads happen in pass 2, after the in-loop barrier

  for (int it = 0; it < NITERS; ++it) {
    // ---- pass 1: info-node var update ----
    if (it == 0) {
      #pragma unroll
      for (int i = 0; i < 2; ++i) {
        if (iok[i]) {
          float2 t = make_float2(tanh_half(Ln[i].x), tanh_half(Ln[i].y));
          sT[pk0[i] & 0xffff] = t;
          sT[pk1[i] & 0xffff] = t;
          sT[pk2[i] & 0xffff] = t;
        }
      }
    } else {
      #pragma unroll
      for (int i = 0; i < 2; ++i) {
        if (iok[i]) {
          int s0 = pk0[i] & 0xffff, c0 = ((unsigned)pk0[i]) >> 16;
          int s1 = pk1[i] & 0xffff, c1 = ((unsigned)pk1[i]) >> 16;
          int s2 = pk2[i] & 0xffff, c2 = ((unsigned)pk2[i]) >> 16;
          float2 P0 = sP[c0], P1 = sP[c1], P2 = sP[c2];
          float2 t0 = sT[s0], t1 = sT[s1], t2 = sT[s2];
          // lane x
          float p0 = pclip(P0.x, t0.x), p1 = pclip(P1.x, t1.x), p2 = pclip(P2.x, t2.x);
          float a0 = t0.x + p0, a1 = t1.x + p1, a2 = t2.x + p2;
          float b0 = t0.x - p0, b1 = t1.x - p1, b2 = t2.x - p2;
          float Ex = En[i].x;
          float A0 = Ex * (a1 * a2), A1 = Ex * (a0 * a2), A2 = Ex * (a0 * a1);
          float B0 = b1 * b2,        B1 = b0 * b2,        B2 = b0 * b1;
          float n0x = tfloor(__fdividef(A0 - B0, A0 + B0));
          float n1x = tfloor(__fdividef(A1 - B1, A1 + B1));
          float n2x = tfloor(__fdividef(A2 - B2, A2 + B2));
          // lane y
          float q0 = pclip(P0.y, t0.y), q1 = pclip(P1.y, t1.y), q2 = pclip(P2.y, t2.y);
          float c0a = t0.y + q0, c1a = t1.y + q1, c2a = t2.y + q2;
          float d0b = t0.y - q0, d1b = t1.y - q1, d2b = t2.y - q2;
          float Ey = En[i].y;
          float C0 = Ey * (c1a * c2a), C1 = Ey * (c0a * c2a), C2 = Ey * (c0a * c1a);
          float D0 = d1b * d2b,        D1 = d0b * d2b,        D2 = d0b * d1b;
          float n0y = tfloor(__fdividef(C0 - D0, C0 + D0));
          float n1y = tfloor(__fdividef(C1 - D1, C1 + D1));
          float n2y = tfloor(__fdividef(C2 - D2, C2 + D2));
          sT[s0] = make_float2(n0x, n0y);
          sT[s1] = make_float2(n1x, n1y);
          sT[s2] = make_float2(n2x, n2y);
        }
      }
    }
    __syncthreads();
    // ---- pass 2: per-check products (parity factor from register) ----
    {
      float px = qpar0.x, py = qpar0.y;
      for (int e = beg0; e < end0 - 1; ++e) { float2 tt = sT[e]; px *= tt.x; py *= tt.y; }
      sP[tid] = make_float2(px, py);
      if (c1ok) {
        float qx = qpar1.x, qy = qpar1.y;
        for (int e = beg1; e < end1 - 1; ++e) { float2 tt = sT[e]; qx *= tt.x; qy *= tt.y; }
        sP[tid + TB] = make_float2(qx, qy);
      }
    }
    __syncthreads();
  }

  // ---- decide: additive log form (once) ----
  int cw0 = pairId * 2;
  float* o0 = out + (size_t)ncw * KK + (size_t)cw0 * KK;
  float* o1 = o0 + KK;
  #pragma unroll
  for (int i = 0; i < 2; ++i) {
    if (iok[i]) {
      int n = tid + TB * i;
      int s0 = pk0[i] & 0xffff, c0 = ((unsigned)pk0[i]) >> 16;
      int s1 = pk1[i] & 0xffff, c1 = ((unsigned)pk1[i]) >> 16;
      int s2 = pk2[i] & 0xffff, c2 = ((unsigned)pk2[i]) >> 16;
      float2 P0 = sP[c0], P1 = sP[c1], P2 = sP[c2];
      float2 t0 = sT[s0], t1 = sT[s1], t2 = sT[s2];
      float2 L = Ln[i];
      float ax = L.x + atanh2c(P0.x, t0.x) + atanh2c(P1.x, t1.x) + atanh2c(P2.x, t2.x);
      float ay = L.y + atanh2c(P0.y, t0.y) + atanh2c(P1.y, t1.y) + atanh2c(P2.y, t2.y);
      o0[n] = (ax < 0.0f) ? 1.0f : 0.0f;
      o1[n] = (ay < 0.0f) ? 1.0f : 0.0f;
    }
  }
}

// ---------------- launcher ----------------
extern "C" void kernel_launch(void* const* d_in, const int* in_sizes, int n_in,
                              void* d_out, int out_size, void* d_ws, size_t ws_size,
                              hipStream_t stream) {
  const float* ebno = (const float*)d_in[1];
  const int*   b    = (const int*)d_in[2];
  const int*   P    = (const int*)d_in[3];
  const int*   cn   = (const int*)d_in[4];
  const int*   vn   = (const int*)d_in[5];
  const float* h_re = (const float*)d_in[6];
  const float* h_im = (const float*)d_in[7];
  const float* nre  = (const float*)d_in[8];
  const float* nim  = (const float*)d_in[9];
  float* out = (float*)d_out;

  int E     = in_sizes[4];
  int batch = in_sizes[2] / (4 * KK);
  int ncw   = batch * 4;
  int T     = batch * NSYM;

  char* ws = (char*)d_ws;
  size_t off = 0;
  auto alloc = [&](size_t bytes) -> void* {
    void* p = ws + off;
    off += (bytes + 255) & ~(size_t)255;
    return p;
  };
  float*    Lch3   = (float*)alloc((size_t)NNODES * ncw * 4);
  unsigned* Ppack  = (unsigned*)alloc((size_t)MM * 16 * 4);
  unsigned* bpack  = (unsigned*)alloc((size_t)ncw * 16 * 4);
  int*      coff   = (int*)alloc((size_t)(MM + 1) * 4);
  int*      cinfo  = (int*)alloc((size_t)EMAX * 4);
  int*      vlist  = (int*)alloc((size_t)NNODES * MAXVDEG * 4);
  double*   nobuf  = (double*)alloc(2 * 8);
  (void)ws_size; (void)n_in; (void)out_size;

  int packItems  = MM * 16 + ncw * 16;
  int packBlocks = (packItems + 511) / 512;
  int bfBlocks   = (ncw * KK + 511) / 512;
  int setupGrid  = 1 + packBlocks + bfBlocks;

  k_setup<<<dim3(setupGrid), dim3(512), 0, stream>>>(cn, vn, E, ebno, P, b, ncw,
                                                     cinfo, vlist, coff, nobuf,
                                                     Ppack, bpack, out, packBlocks);
  k_lmmse<<<dim3((2 * T + LTB - 1) / LTB), dim3(LTB), 0, stream>>>(h_re, h_im, nre, nim, nobuf,
                                                                   bpack, Ppack, Lch3, T, ncw);
  k_bp<<<dim3(ncw / 2), dim3(TB), 0, stream>>>(Lch3, vlist, coff, cinfo, out, E, ncw);
}